// Round 13
// baseline (312.240 us; speedup 1.0000x reference)
//
#include <hip/hip_runtime.h>
#include <hip/hip_fp16.h>
#include <cmath>

#define NN 20000
#define FF 128
#define EE 32768
#define RR 8

#define OUT_X (NN*FF)            // 2,560,000
#define OUT_M (NN*FF + NN*12)    // 2,800,000

typedef _Float16 half8 __attribute__((ext_vector_type(8)));
typedef float f32x4 __attribute__((ext_vector_type(4)));

#define MFMA16(a,b,c) __builtin_amdgcn_mfma_f32_16x16x32_f16(a, b, c, 0, 0, 0)

__device__ __forceinline__ float silu_f(float x) {
#if __has_builtin(__builtin_amdgcn_rcpf)
    return x * __builtin_amdgcn_rcpf(1.0f + __expf(-x));
#else
    return x / (1.0f + __expf(-x));
#endif
}
__device__ __forceinline__ unsigned short f2h(float x) {
    _Float16 h = (_Float16)x;
    return __builtin_bit_cast(unsigned short, h);
}
__device__ __forceinline__ float h2f(unsigned short u) {
    return (float)__builtin_bit_cast(_Float16, u);
}

__device__ __forceinline__ void seg_atomic(unsigned short* p, unsigned bits) {
#if __has_builtin(__builtin_amdgcn_flat_atomic_fadd_v2f16)
    typedef _Float16 v2h __attribute__((ext_vector_type(2)));
    v2h v = __builtin_bit_cast(v2h, bits);
    __builtin_amdgcn_flat_atomic_fadd_v2f16((v2h*)p, v);
#else
    __half2 v = __builtin_bit_cast(__half2, bits);
    unsafeAtomicAdd((__half2*)p, v);
#endif
}

__device__ __forceinline__ void zero4(f32x4 acc[4][2]) {
#pragma unroll
    for (int m = 0; m < 4; m++) { acc[m][0] = (f32x4)0.f; acc[m][1] = (f32x4)0.f; }
}

// ---- 4-wave (256T) helper: one K-chunk against 2 n-tiles per wave (k_msg) ----
__device__ __forceinline__ void mfma_chunk(const unsigned short* __restrict__ Bp, int c,
                                           int wid, int q, int n16,
                                           const half8 a[4], f32x4 acc[4][2])
{
    const unsigned short* bb = Bp + (size_t)(((c * 8 + 2 * wid) * 4) + q) * 128 + n16 * 8;
    half8 b0 = *(const half8*)bb;
    half8 b1 = *(const half8*)(bb + 512);
#pragma unroll
    for (int m = 0; m < 4; m++) {
        acc[m][0] = MFMA16(a[m], b0, acc[m][0]);
        acc[m][1] = MFMA16(a[m], b1, acc[m][1]);
    }
}

// ---- 8-wave (512T) helpers: one n-tile per wave (tile index = wid), M m-tiles ----
template<int M>
__device__ __forceinline__ void mfma_c8(const unsigned short* __restrict__ Bp, int c,
                                        int wid, int q, int n16,
                                        const half8 a[M], f32x4 acc[M])
{
    const unsigned short* bb = Bp + (size_t)(((c * 8 + wid) * 4) + q) * 128 + n16 * 8;
    half8 b0 = *(const half8*)bb;
#pragma unroll
    for (int m = 0; m < M; m++) acc[m] = MFMA16(a[m], b0, acc[m]);
}
template<int M>
__device__ __forceinline__ void mfma_c8_dual(const unsigned short* __restrict__ B1,
                                             const unsigned short* __restrict__ B2, int c,
                                             int wid, int q, int n16,
                                             const half8 a[M], f32x4 acc1[M], f32x4 acc2[M])
{
    const size_t off = (size_t)(((c * 8 + wid) * 4) + q) * 128 + n16 * 8;
    half8 b1 = *(const half8*)(B1 + off);
    half8 b2 = *(const half8*)(B2 + off);
#pragma unroll
    for (int m = 0; m < M; m++) {
        acc1[m] = MFMA16(a[m], b1, acc1[m]);
        acc2[m] = MFMA16(a[m], b2, acc2[m]);
    }
}

// ---------- stride-128 XOR-swizzled LDS helpers (k_msg) ----------
__device__ __forceinline__ int swzb(int row, int bcol) {
    return row * 256 + (bcol ^ ((row & 7) << 4));
}
#define SH8(buf,row,bcol)  (*(half8*)((char*)(buf) + swzb((row),(bcol))))
#define SH16(buf,row,bcol) (*(unsigned short*)((char*)(buf) + swzb((row),(bcol))))
#define SH32(buf,row,bcol) (*(unsigned*)((char*)(buf) + swzb((row),(bcol))))

template<int NCH>
__device__ __forceinline__ void gemm_lds_s(const unsigned short* __restrict__ Bp,
                                           const unsigned short* sA,
                                           int wid, int q, int n16, f32x4 acc[4][2])
{
#pragma unroll
    for (int c = 0; c < NCH; c++) {
        half8 a[4];
#pragma unroll
        for (int m = 0; m < 4; m++)
            a[m] = SH8(sA, m * 16 + n16, c * 64 + q * 16);
        mfma_chunk(Bp, c, wid, q, n16, a, acc);
    }
}

// dual-B GEMM from swizzled LDS: A loaded once, two weight matrices accumulated
template<int NCH>
__device__ __forceinline__ void gemm_lds_s_dual(const unsigned short* __restrict__ B1,
                                                const unsigned short* __restrict__ B2,
                                                const unsigned short* sA,
                                                int wid, int q, int n16,
                                                f32x4 acc1[4][2], f32x4 acc2[4][2])
{
#pragma unroll
    for (int c = 0; c < NCH; c++) {
        half8 a[4];
#pragma unroll
        for (int m = 0; m < 4; m++)
            a[m] = SH8(sA, m * 16 + n16, c * 64 + q * 16);
        mfma_chunk(B1, c, wid, q, n16, a, acc1);
        mfma_chunk(B2, c, wid, q, n16, a, acc2);
    }
}

__device__ __forceinline__ void store_act4_s(f32x4 acc[4][2], const float* __restrict__ bias,
                                             unsigned short* sOut, int n16, int q, int wid, bool dosilu)
{
#pragma unroll
    for (int i = 0; i < 2; i++) {
        const int n = (2 * wid + i) * 16 + n16;
        const float bb = bias ? bias[n] : 0.f;
#pragma unroll
        for (int m = 0; m < 4; m++)
#pragma unroll
            for (int rr = 0; rr < 4; rr++) {
                float v = acc[m][i][rr] + bb;
                if (dosilu) v = silu_f(v);
                SH16(sOut, m * 16 + q * 4 + rr, n * 2) = f2h(v);
            }
    }
}

// ============ merged weight-pack + workspace-zero kernel (1963 blocks) ============
#define PACK_NB 1616
#define ZERO_F4 355032   // (20128 f32 + 2,800,000 u16) / 4 f32 per float4
#define ZERO_NB 347
__global__ __launch_bounds__(256) void k_pack_all(
    const float* __restrict__ Wm1, const float* __restrict__ Wm2,
    const float* __restrict__ Wn1, const float* __restrict__ Wn2,
    const float* __restrict__ We1, const float* __restrict__ Wc1,
    const float* __restrict__ Wrel, const float* __restrict__ Wc2,
    const float* __restrict__ bm1, float* __restrict__ zbase,
    unsigned short* __restrict__ Wm1ap, unsigned short* __restrict__ Wm1bp,
    unsigned short* __restrict__ Wm1xp, unsigned short* __restrict__ Wm2p,
    unsigned short* __restrict__ Wn1p, unsigned short* __restrict__ Wn2p,
    unsigned short* __restrict__ We1ap, unsigned short* __restrict__ We1bp,
    unsigned short* __restrict__ Wc1p, unsigned short* __restrict__ Wrelp,
    unsigned short* __restrict__ Wc2p)
{
    const int bid = blockIdx.x;
    if (bid >= PACK_NB) {   // workspace zeroing path (replaces hipMemsetAsync)
        const int i = (bid - PACK_NB) * 1024 + threadIdx.x * 4;
        if (i < ZERO_F4 * 4) {
            float4 z = { 0.f, 0.f, 0.f, 0.f };
            *(float4*)(zbase + i) = z;
#pragma unroll
            for (int t = 1; t < 4; t++) {
                const int ii = i + t * 1024;
                if (ii < ZERO_F4 * 4) *(float4*)(zbase + ii) = z;
            }
        }
        return;
    }
    const float* W; unsigned short* dst; int K; int pbase;
    const float* bias = nullptr;   // if set, row K of the packed tile = bias
    if (bid < 64)       { W = Wm1;             dst = Wm1ap; K = 128; pbase = bid; }
    else if (bid < 128) { W = Wm1 + 128 * 128; dst = Wm1bp; K = 128; pbase = bid - 64; }
    else if (bid < 144) { W = Wm1 + 256 * 128; dst = Wm1xp; K = 17;  pbase = bid - 128; bias = bm1; }
    else if (bid < 208) { W = Wm2;             dst = Wm2p;  K = 128; pbase = bid - 144; }
    else if (bid < 336) { W = Wn1;             dst = Wn1p;  K = 256; pbase = bid - 208; }
    else if (bid < 400) { W = Wn2;             dst = Wn2p;  K = 128; pbase = bid - 336; }
    else if (bid < 464) { W = We1;             dst = We1ap; K = 128; pbase = bid - 400; }
    else if (bid < 528) { W = We1 + 129 * 128; dst = We1bp; K = 128; pbase = bid - 464; }
    else if (bid < 1040) {
        const int b = (bid - 528) >> 6;
        W = Wc1 + (size_t)b * 16384; dst = Wc1p + (size_t)b * 16384; K = 128; pbase = (bid - 528) & 63;
    }
    else if (bid < 1552) {
        const int b = (bid - 1040) >> 6;
        W = Wrel + (size_t)b * 16384; dst = Wrelp + (size_t)b * 16384; K = 128; pbase = (bid - 1040) & 63;
    }
    else {  // Wc2: pre-scaled single n-tile pack, 8 r x 8 blocks
        const int idx = bid - 1552;
        const int r = idx >> 3;
        const int p = (idx & 7) * 256 + threadIdx.x;   // 0..2047
        const int j = p & 7, n16 = (p >> 3) & 15, q = (p >> 7) & 3, c = (p >> 9) & 3;
        const int k = c * 32 + q * 8 + j;
        float v = (n16 < 4) ? Wc2[(size_t)r * 512 + k * 4 + n16] * 256.0f : 0.f;
        Wc2p[(size_t)r * 2048 + p] = f2h(v);
        return;
    }
    const int p = pbase * 256 + threadIdx.x;
    const int j = p & 7, n16 = (p >> 3) & 15, q = (p >> 7) & 3, t = (p >> 9) & 7, c = p >> 12;
    const int k = c * 32 + q * 8 + j;
    const int n = t * 16 + n16;
    float v = (k < K) ? W[(size_t)k * 128 + n] : 0.f;
    if (bias && k == K) v = bias[n];
    dst[p] = f2h(v);
}

// ============ fused pre-work: prep (625 blocks, 32 nodes) + norm (128 blocks) ============
#define PREP_NB 625
__global__ __launch_bounds__(512, 4) void k_pre(
    const float* __restrict__ h, const float* __restrict__ coord,
    const int* __restrict__ edges,
    const unsigned short* __restrict__ Wm1ap, const unsigned short* __restrict__ Wm1bp,
    unsigned short* __restrict__ h_bf,
    unsigned short* __restrict__ H1, unsigned short* __restrict__ H2,
    float* __restrict__ nsq, float* __restrict__ cnt,
    unsigned short* __restrict__ radh, unsigned short* __restrict__ cdh)
{
    __shared__ __align__(16) unsigned short shA[32 * 136];
    __shared__ __align__(16) unsigned short shO[32 * 136];
    const int tid = threadIdx.x;
    const int bid = blockIdx.x;

    if (bid < PREP_NB) {
        // ---- prep path: h f32->f16 + H1/H2 dual GEMM, 32 nodes (625*32 = NN exact) ----
        const int lane = tid & 63, wid = tid >> 6;   // wid 0..7 = n-tile
        const int n16 = lane & 15, q = lane >> 4;
        const int n0 = bid * 32;
        const int ko = q * 8;

        for (int i = tid; i < 1024; i += 512) {
            const int row = i >> 5;            // 0..31
            const int c4  = (i & 31) * 4;      // col 0..124
            const int node = n0 + row;
            float4 v = *(const float4*)(h + (size_t)node * 128 + c4);
            unsigned short u[4] = { f2h(v.x), f2h(v.y), f2h(v.z), f2h(v.w) };
            *(uint2*)(h_bf + (size_t)node * 128 + c4) = *(const uint2*)u;
            *(uint2*)(shA + row * 136 + c4) = *(const uint2*)u;
        }
        __syncthreads();

        f32x4 acc1[2], acc2[2];
        acc1[0] = acc1[1] = (f32x4)0.f;
        acc2[0] = acc2[1] = (f32x4)0.f;
#pragma unroll
        for (int c = 0; c < 4; c++) {
            half8 a[2];
#pragma unroll
            for (int m = 0; m < 2; m++)
                a[m] = *(const half8*)(shA + (m * 16 + n16) * 136 + c * 32 + ko);
            mfma_c8_dual<2>(Wm1ap, Wm1bp, c, wid, q, n16, a, acc1, acc2);
        }
        {
            const int n = wid * 16 + n16;
#pragma unroll
            for (int m = 0; m < 2; m++)
#pragma unroll
                for (int rr = 0; rr < 4; rr++)
                    shO[(m * 16 + q * 4 + rr) * 136 + n] = f2h(acc1[m][rr]);
        }
        __syncthreads();
        {   // 512 slots = 512 threads, single iteration
            const int e = tid >> 4, c8 = (tid & 15) * 8;
            *(half8*)(H1 + (size_t)(n0 + e) * 128 + c8) = *(const half8*)(shO + e * 136 + c8);
        }
        __syncthreads();
        {
            const int n = wid * 16 + n16;
#pragma unroll
            for (int m = 0; m < 2; m++)
#pragma unroll
                for (int rr = 0; rr < 4; rr++)
                    shO[(m * 16 + q * 4 + rr) * 136 + n] = f2h(acc2[m][rr]);
        }
        __syncthreads();
        {
            const int e = tid >> 4, c8 = (tid & 15) * 8;
            *(half8*)(H2 + (size_t)(n0 + e) * 128 + c8) = *(const half8*)(shO + e * 136 + c8);
        }
    } else {
        // ---- norm path: radial norm + cd/radial f16 tables + cnt, 2048 edges/block ----
        const int nb = bid - PREP_NB;          // 0..127
        const int r = nb >> 4;
        const int e0 = (nb & 15) * 2048;
        const int* rows = edges + r * 2 * EE;
        const int* cols = rows + EE;
        float acc[16];
#pragma unroll
        for (int i = 0; i < 16; i++) acc[i] = 0.f;
        for (int e = e0 + tid; e < e0 + 2048; e += 512) {
            const int rowi = rows[e];
            const float4* cr = (const float4*)(coord + (size_t)rowi * 12);
            const float4* cc = (const float4*)(coord + (size_t)cols[e] * 12);
            float4 a0 = cr[0], a1 = cr[1], a2 = cr[2];
            float4 b0 = cc[0], b1 = cc[1], b2 = cc[2];
            float cd[12] = { a0.x-b0.x, a0.y-b0.y, a0.z-b0.z, a0.w-b0.w,
                             a1.x-b1.x, a1.y-b1.y, a1.z-b1.z, a1.w-b1.w,
                             a2.x-b2.x, a2.y-b2.y, a2.z-b2.z, a2.w-b2.w };
            unsigned short rbuf[16], cbuf[16];
#pragma unroll
            for (int c = 0; c < 4; c++)
#pragma unroll
                for (int d = 0; d < 4; d++) {
                    float v = cd[c*3]*cd[d*3] + cd[c*3+1]*cd[d*3+1] + cd[c*3+2]*cd[d*3+2];
                    acc[c*4+d] += v * v;
                    rbuf[c*4+d] = f2h(v);
                }
#pragma unroll
            for (int i = 0; i < 12; i++) cbuf[i] = f2h(cd[i]);
#pragma unroll
            for (int i = 12; i < 16; i++) cbuf[i] = 0;
            const size_t eg = (size_t)r * EE + e;
            *(half8*)(radh + eg * 16)     = *(const half8*)rbuf;
            *(half8*)(radh + eg * 16 + 8) = *(const half8*)(rbuf + 8);
            *(half8*)(cdh + eg * 16)      = *(const half8*)cbuf;
            *(half8*)(cdh + eg * 16 + 8)  = *(const half8*)(cbuf + 8);
            atomicAdd(&cnt[rowi], 1.0f);   // moved out of k_msg
        }
#pragma unroll
        for (int i = 0; i < 16; i++) {
            float v = acc[i];
            for (int off = 32; off; off >>= 1) v += __shfl_down(v, off, 64);
            if ((tid & 63) == 0) atomicAdd(&nsq[r * 16 + i], v);
        }
    }
}

// ============ message MLP + phi + Wrel-fused agg (f16) + scatters (64 edges/block) ============
__global__ __launch_bounds__(256, 4) void k_msg(
    const unsigned short* __restrict__ H1, const unsigned short* __restrict__ H2,
    const unsigned short* __restrict__ radh, const unsigned short* __restrict__ cdh,
    const float* __restrict__ eattr, const int* __restrict__ edges,
    const float* __restrict__ nsq,
    const unsigned short* __restrict__ Wm1xp,
    const unsigned short* __restrict__ Wm2p, const float* __restrict__ bm2,
    const unsigned short* __restrict__ Wc1p, const float* __restrict__ bc1,
    const unsigned short* __restrict__ Wc2p, const unsigned short* __restrict__ Wrelp,
    unsigned short* __restrict__ sAccH,
    unsigned short* __restrict__ aggh)
{
    __shared__ __align__(16) unsigned short shX[64 * 40];    // 5120 B, dead after phase B
    __shared__ __align__(16) unsigned short shT[64 * 128];   // 16384 B, XOR-swizzled
    __shared__ __align__(16) unsigned short shE[64 * 128];   // 16384 B, XOR-swizzled
    __shared__ __align__(16) unsigned short shCd16[64 * 16]; // 2048 B (f16 cd)
    __shared__ int shRow[64], shCol[64];
    __shared__ float shInv[16];
    float* shPhi = (float*)shX;    // overlay: written only after shX's last read

    const int tid = threadIdx.x;
    const int lane = tid & 63, wid = tid >> 6;
    const int n16 = lane & 15, q = lane >> 4;
    const int r = blockIdx.y;
    const int e0 = blockIdx.x * 64;
    const int ko = q * 8;

    if (tid < 64) shRow[tid] = edges[r * 2 * EE + e0 + tid];
    else if (tid < 128) shCol[tid - 64] = edges[r * 2 * EE + EE + e0 + (tid - 64)];
    else if (tid < 144) {
        const float n = sqrtf(nsq[r * 16 + (tid - 128)]);
        shInv[tid - 128] = 1.0f / fmaxf(n, 1e-12f);
    }
    __syncthreads();

    // phase A: coalesced radial/cd loads (tid<64) + Hsum gather (all threads)
    if (tid < 64) {
        const int e = tid;
        const size_t eg = (size_t)r * EE + e0 + e;
        half8 rv0 = *(const half8*)(radh + eg * 16);
        half8 rv1 = *(const half8*)(radh + eg * 16 + 8);
#pragma unroll
        for (int k2 = 0; k2 < 8; k2++) shX[e * 40 + k2]     = f2h((float)rv0[k2] * shInv[k2]);
#pragma unroll
        for (int k2 = 0; k2 < 8; k2++) shX[e * 40 + 8 + k2] = f2h((float)rv1[k2] * shInv[8 + k2]);
        shX[e * 40 + 16] = f2h(eattr[(size_t)r * EE + e0 + e]);
        shX[e * 40 + 17] = f2h(1.0f);        // bias row (bm1 folded into Wm1xp)
#pragma unroll
        for (int k2 = 18; k2 < 32; k2++) shX[e * 40 + k2] = 0;
        *(half8*)&shCd16[e * 16]     = *(const half8*)(cdh + eg * 16);
        *(half8*)&shCd16[e * 16 + 8] = *(const half8*)(cdh + eg * 16 + 8);
    }
    // Hsum = H1[row] + H2[col]  (64 edges x 16 half8-chunks)
    for (int t = tid; t < 1024; t += 256) {
        const int e = t >> 4, c8 = (t & 15) * 8;
        half8 v1 = *(const half8*)(H1 + (size_t)shRow[e] * 128 + c8);
        half8 v2 = *(const half8*)(H2 + (size_t)shCol[e] * 128 + c8);
        SH8(shT, e, c8 * 2) = v1 + v2;
    }
    __syncthreads();

    // phase B: X-part GEMM (1 chunk, bias folded) + in-place t1 = silu(Hsum + Xpart)
    f32x4 acc[4][2];
    zero4(acc);
    {
        half8 a[4];
#pragma unroll
        for (int m = 0; m < 4; m++) a[m] = *(const half8*)(shX + (m * 16 + n16) * 40 + ko);
        mfma_chunk(Wm1xp, 0, wid, q, n16, a, acc);
    }
#pragma unroll
    for (int i = 0; i < 2; i++) {
        const int n = (2 * wid + i) * 16 + n16;
#pragma unroll
        for (int m = 0; m < 4; m++)
#pragma unroll
            for (int rr = 0; rr < 4; rr++) {
                const int row = m * 16 + q * 4 + rr;
                const float v = h2f(SH16(shT, row, n * 2)) + acc[m][i][rr];
                SH16(shT, row, n * 2) = f2h(silu_f(v));
            }
    }
    __syncthreads();

    zero4(acc);
    gemm_lds_s<4>(Wm2p, shT, wid, q, n16, acc);
    store_act4_s(acc, bm2, shE, n16, q, wid, true);     // ef
    __syncthreads();

    // Dual GEMM: P = ef @ Wrel[r] (acc) and hid-pre = ef @ Wc1[r] (accC), A loaded once.
    // P -> shT, row-local packed-f16 atomics into aggh drain while accC waits in regs.
    f32x4 accC[4][2];
    zero4(acc);
    zero4(accC);
    gemm_lds_s_dual<4>(Wrelp + (size_t)r * 16384, Wc1p + (size_t)r * 16384,
                       shE, wid, q, n16, acc, accC);
    store_act4_s(acc, nullptr, shT, n16, q, wid, false);
    __syncthreads();
    for (int it = tid; it < 64 * 64; it += 256) {
        const int e = it >> 6, jj = it & 63;      // one wave covers one 256B agg row
        const unsigned bits = SH32(shT, e, jj * 4);
        seg_atomic(aggh + (size_t)shRow[e] * 128 + jj * 2, bits);
    }
    __syncthreads();   // all shT reads done; overwrite with hid below

    store_act4_s(accC, bc1 + r * 128, shT, n16, q, wid, true);  // hid
    __syncthreads();

    // phi = hid @ Wc2p[r] / 256  (wave handles m-tile = wid)
    {
        f32x4 ap = (f32x4)0.f;
        const unsigned short* Bw = Wc2p + (size_t)r * 2048;
#pragma unroll
        for (int c = 0; c < 4; c++) {
            half8 a = SH8(shT, wid * 16 + n16, c * 64 + q * 16);
            half8 b = *(const half8*)(Bw + (c * 4 + q) * 128 + n16 * 8);
            ap = MFMA16(a, b, ap);
        }
        if (n16 < 4) {
#pragma unroll
            for (int rr = 0; rr < 4; rr++)
                shPhi[(wid * 16 + q * 4 + rr) * 4 + n16] = ap[rr] * (1.0f / 256.0f);
        }
    }
    __syncthreads();

    // coord scatter: row-local packed-f16 — 8 lanes cover one edge's 6 dwords
    for (int it = tid; it < 512; it += 256) {
        const int e = it >> 3, s2 = it & 7;
        if (s2 < 6) {
            const int s = s2 * 2;
            const int c0 = (s * 86) >> 8;          // s/3
            const int c1 = ((s + 1) * 86) >> 8;
            const float v0 = h2f(shCd16[e * 16 + s])     * shPhi[e * 4 + c0];
            const float v1 = h2f(shCd16[e * 16 + s + 1]) * shPhi[e * 4 + c1];
            unsigned short u[2] = { f2h(v0), f2h(v1) };
            seg_atomic(sAccH + (size_t)shRow[e] * 12 + s, *(const unsigned*)u);
        }
    }
}

// ============ node: node MLP (h_bf | agg f16) + coord + dual p1/p2 (32 nodes, 512T) ============
__global__ __launch_bounds__(512, 4) void k_node(
    const float* __restrict__ h, const unsigned short* __restrict__ h_bf,
    const float* __restrict__ coord,
    const unsigned short* __restrict__ aggh, const unsigned short* __restrict__ sAccH,
    const float* __restrict__ cnt,
    const unsigned short* __restrict__ Wn1p, const float* __restrict__ bn1,
    const unsigned short* __restrict__ Wn2p, const float* __restrict__ bn2,
    const unsigned short* __restrict__ We1ap, const unsigned short* __restrict__ We1bp,
    float* __restrict__ out, unsigned short* __restrict__ p1h, unsigned short* __restrict__ p2h)
{
    __shared__ __align__(16) unsigned short shAgg[32 * 136];
    __shared__ __align__(16) unsigned short shT[32 * 136];
    const int tid = threadIdx.x;
    const int lane = tid & 63, wid = tid >> 6;     // wid 0..7 = n-tile
    const int n16 = lane & 15, q = lane >> 4;
    const int n0 = blockIdx.x * 32;                // 625*32 = NN exact
    const int ko = q * 8;

    int nodeA[2];
#pragma unroll
    for (int m = 0; m < 2; m++) nodeA[m] = n0 + m * 16 + n16;

    // Wn1: K=256 = h_bf (4 chunks) | aggh (4 chunks)
    f32x4 acc[2];
    acc[0] = acc[1] = (f32x4)0.f;
#pragma unroll
    for (int c = 0; c < 4; c++) {
        half8 a[2];
#pragma unroll
        for (int m = 0; m < 2; m++)
            a[m] = *(const half8*)(h_bf + (size_t)nodeA[m] * 128 + c * 32 + ko);
        mfma_c8<2>(Wn1p, c, wid, q, n16, a, acc);
    }
#pragma unroll
    for (int c = 4; c < 8; c++) {
        half8 a[2];
#pragma unroll
        for (int m = 0; m < 2; m++)
            a[m] = *(const half8*)(aggh + (size_t)nodeA[m] * 128 + (c - 4) * 32 + ko);
        mfma_c8<2>(Wn1p, c, wid, q, n16, a, acc);
    }
    {
        const int n = wid * 16 + n16;
        const float bb = bn1[n];
#pragma unroll
        for (int m = 0; m < 2; m++)
#pragma unroll
            for (int rr = 0; rr < 4; rr++)
                shT[(m * 16 + q * 4 + rr) * 136 + n] = f2h(silu_f(acc[m][rr] + bb));
    }
    __syncthreads();

    // Wn2 from shT -> h_new (out f32 + f16 stage in shAgg)
    acc[0] = acc[1] = (f32x4)0.f;
#pragma unroll
    for (int c = 0; c < 4; c++) {
        half8 a[2];
#pragma unroll
        for (int m = 0; m < 2; m++)
            a[m] = *(const half8*)(shT + (m * 16 + n16) * 136 + c * 32 + ko);
        mfma_c8<2>(Wn2p, c, wid, q, n16, a, acc);
    }
    {
        const int n = wid * 16 + n16;
        const float bb = bn2[n];
#pragma unroll
        for (int m = 0; m < 2; m++)
#pragma unroll
            for (int rr = 0; rr < 4; rr++) {
                const int node = n0 + m * 16 + q * 4 + rr;
                const float v = h[(size_t)node * 128 + n] + acc[m][rr] + bb;
                shAgg[(m * 16 + q * 4 + rr) * 136 + n] = f2h(v);
                out[(size_t)node * 128 + n] = v;
            }
    }
    if (tid < 32) {
        const int node = n0 + tid;
        const float ic = 1.0f / fmaxf(cnt[node], 1.0f);
#pragma unroll
        for (int j2 = 0; j2 < 12; j2++)
            out[OUT_X + (size_t)node * 12 + j2] =
                coord[(size_t)node * 12 + j2] + h2f(sAccH[(size_t)node * 12 + j2]) * ic;
    }
    __syncthreads();

    // dual hoisted edge-MLP products: A (h_new tile) loaded once for We1a & We1b
    f32x4 acc1[2], acc2[2];
    acc1[0] = acc1[1] = (f32x4)0.f;
    acc2[0] = acc2[1] = (f32x4)0.f;
#pragma unroll
    for (int c = 0; c < 4; c++) {
        half8 a[2];
#pragma unroll
        for (int m = 0; m < 2; m++)
            a[m] = *(const half8*)(shAgg + (m * 16 + n16) * 136 + c * 32 + ko);
        mfma_c8_dual<2>(We1ap, We1bp, c, wid, q, n16, a, acc1, acc2);
    }
    {
        const int n = wid * 16 + n16;
#pragma unroll
        for (int m = 0; m < 2; m++)
#pragma unroll
            for (int rr = 0; rr < 4; rr++)
                shT[(m * 16 + q * 4 + rr) * 136 + n] = f2h(acc1[m][rr]);
    }
    __syncthreads();
    {
        const int e = tid >> 4, c8 = (tid & 15) * 8;
        *(half8*)(p1h + (size_t)(n0 + e) * 128 + c8) = *(const half8*)(shT + e * 136 + c8);
    }
    __syncthreads();
    {
        const int n = wid * 16 + n16;
#pragma unroll
        for (int m = 0; m < 2; m++)
#pragma unroll
            for (int rr = 0; rr < 4; rr++)
                shT[(m * 16 + q * 4 + rr) * 136 + n] = f2h(acc2[m][rr]);
    }
    __syncthreads();
    {
        const int e = tid >> 4, c8 = (tid & 15) * 8;
        *(half8*)(p2h + (size_t)(n0 + e) * 128 + c8) = *(const half8*)(shT + e * 136 + c8);
    }
}

// ============ edge output m: 4 edges per wave, 16 lanes each, f16 gathers ============
__global__ __launch_bounds__(256) void k_edge(
    const unsigned short* __restrict__ p1h, const unsigned short* __restrict__ p2h,
    const float* __restrict__ eattr, const int* __restrict__ edges,
    const float* __restrict__ We1, const float* __restrict__ be1,
    const float* __restrict__ We2, const float* __restrict__ be2,
    float* __restrict__ mout)
{
    const int tid = threadIdx.x;
    const int lane = tid & 63, wid = tid >> 6;
    const int sub = lane >> 4, l16 = lane & 15;
    const int j = l16 * 8;
    const int g0 = blockIdx.x * 256 + wid * 64;   // wave covers 64 consecutive global edges
    const int r = g0 >> 15;                       // EE = 32768
    const int ebase = g0 & (EE - 1);
    const int* rowsP = edges + r * 2 * EE;
    const int* colsP = rowsP + EE;
    const float* ea = eattr + (size_t)r * EE;

    float w2[8], b1v[8], wm[8];
#pragma unroll
    for (int k = 0; k < 8; k++) {
        w2[k]  = We2[j + k];
        b1v[k] = be1[j + k];
        wm[k]  = We1[128 * 128 + j + k];
    }
    const float b2 = be2[0];

#pragma unroll 4
    for (int it = 0; it < 16; ++it) {
        const int e = ebase + it * 4 + sub;
        const int row = rowsP[e], col = colsP[e];
        const float a = ea[e];
        half8 x1 = *(const half8*)(p1h + (size_t)row * 128 + j);
        half8 x2 = *(const half8*)(p2h + (size_t)col * 128 + j);
        float s = 0.f;
#pragma unroll
        for (int k = 0; k < 8; k++) {
            const float v = (float)x1[k] + (float)x2[k] + a * wm[k] + b1v[k];
            s += silu_f(v) * w2[k];
        }
        s += __shfl_xor(s, 1, 64);
        s += __shfl_xor(s, 2, 64);
        s += __shfl_xor(s, 4, 64);
        s += __shfl_xor(s, 8, 64);
        if (l16 == 0) mout[g0 + it * 4 + sub] = s + b2;
    }
}

extern "C" void kernel_launch(void* const* d_in, const int* in_sizes, int n_in,
                              void* d_out, int out_size, void* d_ws, size_t ws_size,
                              hipStream_t stream)
{
    const float* h     = (const float*)d_in[0];
    const float* coord = (const float*)d_in[1];
    const float* eattr = (const float*)d_in[2];
    const int*   edges = (const int*)d_in[3];
    const float* Wm1 = (const float*)d_in[4];
    const float* bm1 = (const float*)d_in[5];
    const float* Wm2 = (const float*)d_in[6];
    const float* bm2 = (const float*)d_in[7];
    const float* We1 = (const float*)d_in[8];
    const float* be1 = (const float*)d_in[9];
    const float* We2 = (const float*)d_in[10];
    const float* be2 = (const float*)d_in[11];
    const float* Wn1 = (const float*)d_in[12];
    const float* bn1 = (const float*)d_in[13];
    const float* Wn2 = (const float*)d_in[14];
    const float* bn2 = (const float*)d_in[15];
    const float* Wrel = (const float*)d_in[16];
    const float* Wc1 = (const float*)d_in[17];
    const float* bc1 = (const float*)d_in[18];
    const float* Wc2 = (const float*)d_in[19];

    float* out = (float*)d_out;
    float* ws  = (float*)d_ws;

    // f32 zero region: nsq(128) | cnt(20000); f16 zero region: aggh | sAccH
    float* nsq      = ws;             // 128
    float* cnt      = ws + 128;       // 20000 -> f32 region ends at 20128
    unsigned short* U = (unsigned short*)(ws + 20128);
    unsigned short* aggh    = U;                   // 2,560,000 (zeroed, f16 accum)
    unsigned short* sAccH   = U + 2560000;         // 240,000  (zeroed, f16 accum)
    unsigned short* h_bf    = U + 2800000;         // 2,560,000
    unsigned short* H1      = U + 5360000;         // 2,560,000
    unsigned short* H2      = U + 7920000;         // 2,560,000
    unsigned short* p1h     = U + 10480000;        // 2,560,000
    unsigned short* p2h     = U + 13040000;        // 2,560,000
    unsigned short* Wm1ap   = U + 15600000;        // 16,384
    unsigned short* Wm1bp   = U + 15616384;        // 16,384
    unsigned short* Wm1xp   = U + 15632768;        // 4,096
    unsigned short* Wm2p    = U + 15636864;        // 16,384
    unsigned short* Wn1p    = U + 15653248;        // 32,768
    unsigned short* Wn2p    = U + 15686016;        // 16,384
    unsigned short* We1ap   = U + 15702400;        // 16,384
    unsigned short* We1bp   = U + 15718784;        // 16,384
    unsigned short* Wc1p    = U + 15735168;        // 131,072
    unsigned short* Wrelp   = U + 15866240;        // 131,072
    unsigned short* Wc2p    = U + 15997312;        // 16,384 -> ends 16,013,696 shorts

    // cd/radial f16 tables live in DEAD regions (written by k_pre norm path, read by
    // k_msg, overwritten only afterwards by k_node):
    unsigned short* radh = (unsigned short*)out;   // d_out h_new region (8.39 MB)
    unsigned short* cdh  = p1h;                    // p1h/p2h region (8.39 MB)

    // zeroing of [ws, ws + 20128 f32 + 2,800,000 u16) is done inside k_pack_all

    k_pack_all<<<PACK_NB + ZERO_NB, 256, 0, stream>>>(
        Wm1, Wm2, Wn1, Wn2, We1, Wc1, Wrel, Wc2, bm1, ws,
        Wm1ap, Wm1bp, Wm1xp, Wm2p, Wn1p, Wn2p, We1ap, We1bp, Wc1p, Wrelp, Wc2p);
    k_pre<<<PREP_NB + 128, 512, 0, stream>>>(h, coord, edges, Wm1ap, Wm1bp,
        h_bf, H1, H2, nsq, cnt, radh, cdh);
    k_msg<<<dim3(EE / 64, RR), 256, 0, stream>>>(H1, H2, radh, cdh, eattr, edges, nsq,
        Wm1xp, Wm2p, bm2, Wc1p, bc1, Wc2p, Wrelp, sAccH, aggh);
    k_node<<<NN / 32, 512, 0, stream>>>(h, h_bf, coord, aggh, sAccH, cnt,
        Wn1p, bn1, Wn2p, bn2, We1ap, We1bp, out, p1h, p2h);
    k_edge<<<dim3((RR * EE) / 256), 256, 0, stream>>>(p1h, p2h, eattr, edges,
        We1, be1, We2, be2, out + OUT_M);
}

// Round 14
// 301.979 us; speedup vs baseline: 1.0340x; 1.0340x over previous
//
#include <hip/hip_runtime.h>
#include <hip/hip_fp16.h>
#include <cmath>

#define NN 20000
#define FF 128
#define EE 32768
#define RR 8

#define OUT_X (NN*FF)            // 2,560,000
#define OUT_M (NN*FF + NN*12)    // 2,800,000

typedef _Float16 half8 __attribute__((ext_vector_type(8)));
typedef float f32x4 __attribute__((ext_vector_type(4)));

#define MFMA16(a,b,c) __builtin_amdgcn_mfma_f32_16x16x32_f16(a, b, c, 0, 0, 0)

__device__ __forceinline__ float silu_f(float x) {
#if __has_builtin(__builtin_amdgcn_rcpf)
    return x * __builtin_amdgcn_rcpf(1.0f + __expf(-x));
#else
    return x / (1.0f + __expf(-x));
#endif
}
__device__ __forceinline__ unsigned short f2h(float x) {
    _Float16 h = (_Float16)x;
    return __builtin_bit_cast(unsigned short, h);
}
__device__ __forceinline__ float h2f(unsigned short u) {
    return (float)__builtin_bit_cast(_Float16, u);
}

__device__ __forceinline__ void seg_atomic(unsigned short* p, unsigned bits) {
#if __has_builtin(__builtin_amdgcn_flat_atomic_fadd_v2f16)
    typedef _Float16 v2h __attribute__((ext_vector_type(2)));
    v2h v = __builtin_bit_cast(v2h, bits);
    __builtin_amdgcn_flat_atomic_fadd_v2f16((v2h*)p, v);
#else
    __half2 v = __builtin_bit_cast(__half2, bits);
    unsafeAtomicAdd((__half2*)p, v);
#endif
}

__device__ __forceinline__ void zero4(f32x4 acc[4][2]) {
#pragma unroll
    for (int m = 0; m < 4; m++) { acc[m][0] = (f32x4)0.f; acc[m][1] = (f32x4)0.f; }
}

// ---- 4-wave (256T) helper: one K-chunk against 2 n-tiles per wave (k_msg) ----
__device__ __forceinline__ void mfma_chunk(const unsigned short* __restrict__ Bp, int c,
                                           int wid, int q, int n16,
                                           const half8 a[4], f32x4 acc[4][2])
{
    const unsigned short* bb = Bp + (size_t)(((c * 8 + 2 * wid) * 4) + q) * 128 + n16 * 8;
    half8 b0 = *(const half8*)bb;
    half8 b1 = *(const half8*)(bb + 512);
#pragma unroll
    for (int m = 0; m < 4; m++) {
        acc[m][0] = MFMA16(a[m], b0, acc[m][0]);
        acc[m][1] = MFMA16(a[m], b1, acc[m][1]);
    }
}

// ---- 8-wave (512T) helpers: one n-tile per wave (tile index = wid), M m-tiles ----
template<int M>
__device__ __forceinline__ void mfma_c8(const unsigned short* __restrict__ Bp, int c,
                                        int wid, int q, int n16,
                                        const half8 a[M], f32x4 acc[M])
{
    const unsigned short* bb = Bp + (size_t)(((c * 8 + wid) * 4) + q) * 128 + n16 * 8;
    half8 b0 = *(const half8*)bb;
#pragma unroll
    for (int m = 0; m < M; m++) acc[m] = MFMA16(a[m], b0, acc[m]);
}
template<int M>
__device__ __forceinline__ void mfma_c8_dual(const unsigned short* __restrict__ B1,
                                             const unsigned short* __restrict__ B2, int c,
                                             int wid, int q, int n16,
                                             const half8 a[M], f32x4 acc1[M], f32x4 acc2[M])
{
    const size_t off = (size_t)(((c * 8 + wid) * 4) + q) * 128 + n16 * 8;
    half8 b1 = *(const half8*)(B1 + off);
    half8 b2 = *(const half8*)(B2 + off);
#pragma unroll
    for (int m = 0; m < M; m++) {
        acc1[m] = MFMA16(a[m], b1, acc1[m]);
        acc2[m] = MFMA16(a[m], b2, acc2[m]);
    }
}

// ---------- stride-128 XOR-swizzled LDS helpers (k_msg) ----------
__device__ __forceinline__ int swzb(int row, int bcol) {
    return row * 256 + (bcol ^ ((row & 7) << 4));
}
#define SH8(buf,row,bcol)  (*(half8*)((char*)(buf) + swzb((row),(bcol))))
#define SH16(buf,row,bcol) (*(unsigned short*)((char*)(buf) + swzb((row),(bcol))))
#define SH32(buf,row,bcol) (*(unsigned*)((char*)(buf) + swzb((row),(bcol))))

template<int NCH>
__device__ __forceinline__ void gemm_lds_s(const unsigned short* __restrict__ Bp,
                                           const unsigned short* sA,
                                           int wid, int q, int n16, f32x4 acc[4][2])
{
#pragma unroll
    for (int c = 0; c < NCH; c++) {
        half8 a[4];
#pragma unroll
        for (int m = 0; m < 4; m++)
            a[m] = SH8(sA, m * 16 + n16, c * 64 + q * 16);
        mfma_chunk(Bp, c, wid, q, n16, a, acc);
    }
}

__device__ __forceinline__ void store_act4_s(f32x4 acc[4][2], const float* __restrict__ bias,
                                             unsigned short* sOut, int n16, int q, int wid, bool dosilu)
{
#pragma unroll
    for (int i = 0; i < 2; i++) {
        const int n = (2 * wid + i) * 16 + n16;
        const float bb = bias ? bias[n] : 0.f;
#pragma unroll
        for (int m = 0; m < 4; m++)
#pragma unroll
            for (int rr = 0; rr < 4; rr++) {
                float v = acc[m][i][rr] + bb;
                if (dosilu) v = silu_f(v);
                SH16(sOut, m * 16 + q * 4 + rr, n * 2) = f2h(v);
            }
    }
}

// ============ merged weight-pack + workspace-zero kernel ============
#define PACK_NB 1616
#define ZERO_F32 1420128   // 20128 f32 + 2,800,000 u16 (aggh + sAccH)
#define ZERO_NB 347        // 347 * 4096 f32 = 1,421,312 >= ZERO_F32
__global__ __launch_bounds__(256) void k_pack_all(
    const float* __restrict__ Wm1, const float* __restrict__ Wm2,
    const float* __restrict__ Wn1, const float* __restrict__ Wn2,
    const float* __restrict__ We1, const float* __restrict__ Wc1,
    const float* __restrict__ Wrel, const float* __restrict__ Wc2,
    const float* __restrict__ bm1, float* __restrict__ zbase,
    unsigned short* __restrict__ Wm1ap, unsigned short* __restrict__ Wm1bp,
    unsigned short* __restrict__ Wm1xp, unsigned short* __restrict__ Wm2p,
    unsigned short* __restrict__ Wn1p, unsigned short* __restrict__ Wn2p,
    unsigned short* __restrict__ We1ap, unsigned short* __restrict__ We1bp,
    unsigned short* __restrict__ Wc1p, unsigned short* __restrict__ Wrelp,
    unsigned short* __restrict__ Wc2p)
{
    const int bid = blockIdx.x;
    if (bid >= PACK_NB) {   // workspace zeroing path (block covers 4096 f32)
        const int base = (bid - PACK_NB) * 4096 + threadIdx.x * 4;
        const float4 z = { 0.f, 0.f, 0.f, 0.f };
#pragma unroll
        for (int t = 0; t < 4; t++) {
            const int ii = base + t * 1024;
            if (ii < ZERO_F32) *(float4*)(zbase + ii) = z;
        }
        return;
    }
    const float* W; unsigned short* dst; int K; int pbase;
    const float* bias = nullptr;   // if set, row K of the packed tile = bias
    if (bid < 64)       { W = Wm1;             dst = Wm1ap; K = 128; pbase = bid; }
    else if (bid < 128) { W = Wm1 + 128 * 128; dst = Wm1bp; K = 128; pbase = bid - 64; }
    else if (bid < 144) { W = Wm1 + 256 * 128; dst = Wm1xp; K = 17;  pbase = bid - 128; bias = bm1; }
    else if (bid < 208) { W = Wm2;             dst = Wm2p;  K = 128; pbase = bid - 144; }
    else if (bid < 336) { W = Wn1;             dst = Wn1p;  K = 256; pbase = bid - 208; }
    else if (bid < 400) { W = Wn2;             dst = Wn2p;  K = 128; pbase = bid - 336; }
    else if (bid < 464) { W = We1;             dst = We1ap; K = 128; pbase = bid - 400; }
    else if (bid < 528) { W = We1 + 129 * 128; dst = We1bp; K = 128; pbase = bid - 464; }
    else if (bid < 1040) {
        const int b = (bid - 528) >> 6;
        W = Wc1 + (size_t)b * 16384; dst = Wc1p + (size_t)b * 16384; K = 128; pbase = (bid - 528) & 63;
    }
    else if (bid < 1552) {
        const int b = (bid - 1040) >> 6;
        W = Wrel + (size_t)b * 16384; dst = Wrelp + (size_t)b * 16384; K = 128; pbase = (bid - 1040) & 63;
    }
    else {  // Wc2: pre-scaled single n-tile pack, 8 r x 8 blocks
        const int idx = bid - 1552;
        const int r = idx >> 3;
        const int p = (idx & 7) * 256 + threadIdx.x;   // 0..2047
        const int j = p & 7, n16 = (p >> 3) & 15, q = (p >> 7) & 3, c = (p >> 9) & 3;
        const int k = c * 32 + q * 8 + j;
        float v = (n16 < 4) ? Wc2[(size_t)r * 512 + k * 4 + n16] * 256.0f : 0.f;
        Wc2p[(size_t)r * 2048 + p] = f2h(v);
        return;
    }
    const int p = pbase * 256 + threadIdx.x;
    const int j = p & 7, n16 = (p >> 3) & 15, q = (p >> 7) & 3, t = (p >> 9) & 7, c = p >> 12;
    const int k = c * 32 + q * 8 + j;
    const int n = t * 16 + n16;
    float v = (k < K) ? W[(size_t)k * 128 + n] : 0.f;
    if (bias && k == K) v = bias[n];
    dst[p] = f2h(v);
}

// ============ fused pre-work: prep (625 blocks, 32 nodes) + norm (128 blocks) ============
#define PREP_NB 625
__global__ __launch_bounds__(512, 4) void k_pre(
    const float* __restrict__ h, const float* __restrict__ coord,
    const int* __restrict__ edges,
    const unsigned short* __restrict__ Wm1ap, const unsigned short* __restrict__ Wm1bp,
    unsigned short* __restrict__ h_bf,
    unsigned short* __restrict__ H1, unsigned short* __restrict__ H2,
    float* __restrict__ nsq, float* __restrict__ cnt,
    unsigned short* __restrict__ radh, unsigned short* __restrict__ cdh)
{
    __shared__ __align__(16) unsigned short shA[32 * 136];
    __shared__ __align__(16) unsigned short shO[32 * 136];
    const int tid = threadIdx.x;
    const int bid = blockIdx.x;

    if (bid < PREP_NB) {
        // ---- prep path: h f32->f16 + H1/H2 dual GEMM, 32 nodes (625*32 = NN exact) ----
        const int lane = tid & 63, wid = tid >> 6;   // wid 0..7 = n-tile
        const int n16 = lane & 15, q = lane >> 4;
        const int n0 = bid * 32;
        const int ko = q * 8;

        for (int i = tid; i < 1024; i += 512) {
            const int row = i >> 5;            // 0..31
            const int c4  = (i & 31) * 4;      // col 0..124
            const int node = n0 + row;
            float4 v = *(const float4*)(h + (size_t)node * 128 + c4);
            unsigned short u[4] = { f2h(v.x), f2h(v.y), f2h(v.z), f2h(v.w) };
            *(uint2*)(h_bf + (size_t)node * 128 + c4) = *(const uint2*)u;
            *(uint2*)(shA + row * 136 + c4) = *(const uint2*)u;
        }
        __syncthreads();

        f32x4 acc1[2], acc2[2];
        acc1[0] = acc1[1] = (f32x4)0.f;
        acc2[0] = acc2[1] = (f32x4)0.f;
#pragma unroll
        for (int c = 0; c < 4; c++) {
            half8 a[2];
#pragma unroll
            for (int m = 0; m < 2; m++)
                a[m] = *(const half8*)(shA + (m * 16 + n16) * 136 + c * 32 + ko);
            mfma_c8_dual<2>(Wm1ap, Wm1bp, c, wid, q, n16, a, acc1, acc2);
        }
        {
            const int n = wid * 16 + n16;
#pragma unroll
            for (int m = 0; m < 2; m++)
#pragma unroll
                for (int rr = 0; rr < 4; rr++)
                    shO[(m * 16 + q * 4 + rr) * 136 + n] = f2h(acc1[m][rr]);
        }
        __syncthreads();
        {   // 512 slots = 512 threads, single iteration
            const int e = tid >> 4, c8 = (tid & 15) * 8;
            *(half8*)(H1 + (size_t)(n0 + e) * 128 + c8) = *(const half8*)(shO + e * 136 + c8);
        }
        __syncthreads();
        {
            const int n = wid * 16 + n16;
#pragma unroll
            for (int m = 0; m < 2; m++)
#pragma unroll
                for (int rr = 0; rr < 4; rr++)
                    shO[(m * 16 + q * 4 + rr) * 136 + n] = f2h(acc2[m][rr]);
        }
        __syncthreads();
        {
            const int e = tid >> 4, c8 = (tid & 15) * 8;
            *(half8*)(H2 + (size_t)(n0 + e) * 128 + c8) = *(const half8*)(shO + e * 136 + c8);
        }
    } else {
        // ---- norm path: radial norm + cd/radial f16 tables + cnt, 2048 edges/block ----
        const int nb = bid - PREP_NB;          // 0..127
        const int r = nb >> 4;
        const int e0 = (nb & 15) * 2048;
        const int* rows = edges + r * 2 * EE;
        const int* cols = rows + EE;
        float acc[16];
#pragma unroll
        for (int i = 0; i < 16; i++) acc[i] = 0.f;
        for (int e = e0 + tid; e < e0 + 2048; e += 512) {
            const int rowi = rows[e];
            const float4* cr = (const float4*)(coord + (size_t)rowi * 12);
            const float4* cc = (const float4*)(coord + (size_t)cols[e] * 12);
            float4 a0 = cr[0], a1 = cr[1], a2 = cr[2];
            float4 b0 = cc[0], b1 = cc[1], b2 = cc[2];
            float cd[12] = { a0.x-b0.x, a0.y-b0.y, a0.z-b0.z, a0.w-b0.w,
                             a1.x-b1.x, a1.y-b1.y, a1.z-b1.z, a1.w-b1.w,
                             a2.x-b2.x, a2.y-b2.y, a2.z-b2.z, a2.w-b2.w };
            unsigned short rbuf[16], cbuf[16];
#pragma unroll
            for (int c = 0; c < 4; c++)
#pragma unroll
                for (int d = 0; d < 4; d++) {
                    float v = cd[c*3]*cd[d*3] + cd[c*3+1]*cd[d*3+1] + cd[c*3+2]*cd[d*3+2];
                    acc[c*4+d] += v * v;
                    rbuf[c*4+d] = f2h(v);
                }
#pragma unroll
            for (int i = 0; i < 12; i++) cbuf[i] = f2h(cd[i]);
#pragma unroll
            for (int i = 12; i < 16; i++) cbuf[i] = 0;
            const size_t eg = (size_t)r * EE + e;
            *(half8*)(radh + eg * 16)     = *(const half8*)rbuf;
            *(half8*)(radh + eg * 16 + 8) = *(const half8*)(rbuf + 8);
            *(half8*)(cdh + eg * 16)      = *(const half8*)cbuf;
            *(half8*)(cdh + eg * 16 + 8)  = *(const half8*)(cbuf + 8);
            atomicAdd(&cnt[rowi], 1.0f);
        }
#pragma unroll
        for (int i = 0; i < 16; i++) {
            float v = acc[i];
            for (int off = 32; off; off >>= 1) v += __shfl_down(v, off, 64);
            if ((tid & 63) == 0) atomicAdd(&nsq[r * 16 + i], v);
        }
    }
}

// ============ message MLP + phi + Wrel-fused agg (f16) + scatters (64 edges/block) ============
__global__ __launch_bounds__(256, 4) void k_msg(
    const unsigned short* __restrict__ H1, const unsigned short* __restrict__ H2,
    const unsigned short* __restrict__ radh, const unsigned short* __restrict__ cdh,
    const float* __restrict__ eattr, const int* __restrict__ edges,
    const float* __restrict__ nsq,
    const unsigned short* __restrict__ Wm1xp,
    const unsigned short* __restrict__ Wm2p, const float* __restrict__ bm2,
    const unsigned short* __restrict__ Wc1p, const float* __restrict__ bc1,
    const unsigned short* __restrict__ Wc2p, const unsigned short* __restrict__ Wrelp,
    unsigned short* __restrict__ sAccH,
    unsigned short* __restrict__ aggh)
{
    __shared__ __align__(16) unsigned short shX[64 * 40];    // 5120 B, dead after phase B
    __shared__ __align__(16) unsigned short shT[64 * 128];   // 16384 B, XOR-swizzled
    __shared__ __align__(16) unsigned short shE[64 * 128];   // 16384 B, XOR-swizzled
    __shared__ __align__(16) unsigned short shCd16[64 * 16]; // 2048 B (f16 cd)
    __shared__ int shRow[64], shCol[64];
    __shared__ float shInv[16];
    float* shPhi = (float*)shX;    // overlay: written only after shX's last read

    const int tid = threadIdx.x;
    const int lane = tid & 63, wid = tid >> 6;
    const int n16 = lane & 15, q = lane >> 4;
    const int r = blockIdx.y;
    const int e0 = blockIdx.x * 64;
    const int ko = q * 8;

    if (tid < 64) shRow[tid] = edges[r * 2 * EE + e0 + tid];
    else if (tid < 128) shCol[tid - 64] = edges[r * 2 * EE + EE + e0 + (tid - 64)];
    else if (tid < 144) {
        const float n = sqrtf(nsq[r * 16 + (tid - 128)]);
        shInv[tid - 128] = 1.0f / fmaxf(n, 1e-12f);
    }
    __syncthreads();

    // phase A: coalesced radial/cd loads (tid<64) + Hsum gather (all threads)
    if (tid < 64) {
        const int e = tid;
        const size_t eg = (size_t)r * EE + e0 + e;
        half8 rv0 = *(const half8*)(radh + eg * 16);
        half8 rv1 = *(const half8*)(radh + eg * 16 + 8);
#pragma unroll
        for (int k2 = 0; k2 < 8; k2++) shX[e * 40 + k2]     = f2h((float)rv0[k2] * shInv[k2]);
#pragma unroll
        for (int k2 = 0; k2 < 8; k2++) shX[e * 40 + 8 + k2] = f2h((float)rv1[k2] * shInv[8 + k2]);
        shX[e * 40 + 16] = f2h(eattr[(size_t)r * EE + e0 + e]);
        shX[e * 40 + 17] = f2h(1.0f);        // bias row (bm1 folded into Wm1xp)
#pragma unroll
        for (int k2 = 18; k2 < 32; k2++) shX[e * 40 + k2] = 0;
        *(half8*)&shCd16[e * 16]     = *(const half8*)(cdh + eg * 16);
        *(half8*)&shCd16[e * 16 + 8] = *(const half8*)(cdh + eg * 16 + 8);
    }
    // Hsum = H1[row] + H2[col]  (64 edges x 16 half8-chunks)
    for (int t = tid; t < 1024; t += 256) {
        const int e = t >> 4, c8 = (t & 15) * 8;
        half8 v1 = *(const half8*)(H1 + (size_t)shRow[e] * 128 + c8);
        half8 v2 = *(const half8*)(H2 + (size_t)shCol[e] * 128 + c8);
        SH8(shT, e, c8 * 2) = v1 + v2;
    }
    __syncthreads();

    // phase B: X-part GEMM (1 chunk, bias folded) + in-place t1 = silu(Hsum + Xpart)
    f32x4 acc[4][2];
    zero4(acc);
    {
        half8 a[4];
#pragma unroll
        for (int m = 0; m < 4; m++) a[m] = *(const half8*)(shX + (m * 16 + n16) * 40 + ko);
        mfma_chunk(Wm1xp, 0, wid, q, n16, a, acc);
    }
#pragma unroll
    for (int i = 0; i < 2; i++) {
        const int n = (2 * wid + i) * 16 + n16;
#pragma unroll
        for (int m = 0; m < 4; m++)
#pragma unroll
            for (int rr = 0; rr < 4; rr++) {
                const int row = m * 16 + q * 4 + rr;
                const float v = h2f(SH16(shT, row, n * 2)) + acc[m][i][rr];
                SH16(shT, row, n * 2) = f2h(silu_f(v));
            }
    }
    __syncthreads();

    zero4(acc);
    gemm_lds_s<4>(Wm2p, shT, wid, q, n16, acc);
    store_act4_s(acc, bm2, shE, n16, q, wid, true);     // ef
    __syncthreads();

    // Wrel fusion: P = ef @ Wrel[r] -> shT (f16), then row-local packed-f16
    // atomics into aggh; they drain under the Wc1+phi GEMMs.
    zero4(acc);
    gemm_lds_s<4>(Wrelp + (size_t)r * 16384, shE, wid, q, n16, acc);
    store_act4_s(acc, nullptr, shT, n16, q, wid, false);
    __syncthreads();
    for (int it = tid; it < 64 * 64; it += 256) {
        const int e = it >> 6, jj = it & 63;      // one wave covers one 256B agg row
        const unsigned bits = SH32(shT, e, jj * 4);
        seg_atomic(aggh + (size_t)shRow[e] * 128 + jj * 2, bits);
    }
    __syncthreads();   // shT is overwritten by the Wc1 output below

    zero4(acc);
    gemm_lds_s<4>(Wc1p + (size_t)r * 16384, shE, wid, q, n16, acc);
    store_act4_s(acc, bc1 + r * 128, shT, n16, q, wid, true);  // hid
    __syncthreads();

    // phi = hid @ Wc2p[r] / 256  (wave handles m-tile = wid)
    {
        f32x4 ap = (f32x4)0.f;
        const unsigned short* Bw = Wc2p + (size_t)r * 2048;
#pragma unroll
        for (int c = 0; c < 4; c++) {
            half8 a = SH8(shT, wid * 16 + n16, c * 64 + q * 16);
            half8 b = *(const half8*)(Bw + (c * 4 + q) * 128 + n16 * 8);
            ap = MFMA16(a, b, ap);
        }
        if (n16 < 4) {
#pragma unroll
            for (int rr = 0; rr < 4; rr++)
                shPhi[(wid * 16 + q * 4 + rr) * 4 + n16] = ap[rr] * (1.0f / 256.0f);
        }
    }
    __syncthreads();

    // coord scatter: row-local packed-f16 — 8 lanes cover one edge's 6 dwords
    for (int it = tid; it < 512; it += 256) {
        const int e = it >> 3, s2 = it & 7;
        if (s2 < 6) {
            const int s = s2 * 2;
            const int c0 = (s * 86) >> 8;          // s/3
            const int c1 = ((s + 1) * 86) >> 8;
            const float v0 = h2f(shCd16[e * 16 + s])     * shPhi[e * 4 + c0];
            const float v1 = h2f(shCd16[e * 16 + s + 1]) * shPhi[e * 4 + c1];
            unsigned short u[2] = { f2h(v0), f2h(v1) };
            seg_atomic(sAccH + (size_t)shRow[e] * 12 + s, *(const unsigned*)u);
        }
    }
}

// ============ node: node MLP (h_bf | agg f16) + coord + dual p1/p2 (32 nodes, 512T) ============
__global__ __launch_bounds__(512, 4) void k_node(
    const float* __restrict__ h, const unsigned short* __restrict__ h_bf,
    const float* __restrict__ coord,
    const unsigned short* __restrict__ aggh, const unsigned short* __restrict__ sAccH,
    const float* __restrict__ cnt,
    const unsigned short* __restrict__ Wn1p, const float* __restrict__ bn1,
    const unsigned short* __restrict__ Wn2p, const float* __restrict__ bn2,
    const unsigned short* __restrict__ We1ap, const unsigned short* __restrict__ We1bp,
    float* __restrict__ out, unsigned short* __restrict__ p1h, unsigned short* __restrict__ p2h)
{
    __shared__ __align__(16) unsigned short shAgg[32 * 136];
    __shared__ __align__(16) unsigned short shT[32 * 136];
    const int tid = threadIdx.x;
    const int lane = tid & 63, wid = tid >> 6;     // wid 0..7 = n-tile
    const int n16 = lane & 15, q = lane >> 4;
    const int n0 = blockIdx.x * 32;                // 625*32 = NN exact
    const int ko = q * 8;

    int nodeA[2];
#pragma unroll
    for (int m = 0; m < 2; m++) nodeA[m] = n0 + m * 16 + n16;

    // Wn1: K=256 = h_bf (4 chunks) | aggh (4 chunks)
    f32x4 acc[2];
    acc[0] = acc[1] = (f32x4)0.f;
#pragma unroll
    for (int c = 0; c < 4; c++) {
        half8 a[2];
#pragma unroll
        for (int m = 0; m < 2; m++)
            a[m] = *(const half8*)(h_bf + (size_t)nodeA[m] * 128 + c * 32 + ko);
        mfma_c8<2>(Wn1p, c, wid, q, n16, a, acc);
    }
#pragma unroll
    for (int c = 4; c < 8; c++) {
        half8 a[2];
#pragma unroll
        for (int m = 0; m < 2; m++)
            a[m] = *(const half8*)(aggh + (size_t)nodeA[m] * 128 + (c - 4) * 32 + ko);
        mfma_c8<2>(Wn1p, c, wid, q, n16, a, acc);
    }
    {
        const int n = wid * 16 + n16;
        const float bb = bn1[n];
#pragma unroll
        for (int m = 0; m < 2; m++)
#pragma unroll
            for (int rr = 0; rr < 4; rr++)
                shT[(m * 16 + q * 4 + rr) * 136 + n] = f2h(silu_f(acc[m][rr] + bb));
    }
    __syncthreads();

    // Wn2 from shT -> h_new (out f32 + f16 stage in shAgg)
    acc[0] = acc[1] = (f32x4)0.f;
#pragma unroll
    for (int c = 0; c < 4; c++) {
        half8 a[2];
#pragma unroll
        for (int m = 0; m < 2; m++)
            a[m] = *(const half8*)(shT + (m * 16 + n16) * 136 + c * 32 + ko);
        mfma_c8<2>(Wn2p, c, wid, q, n16, a, acc);
    }
    {
        const int n = wid * 16 + n16;
        const float bb = bn2[n];
#pragma unroll
        for (int m = 0; m < 2; m++)
#pragma unroll
            for (int rr = 0; rr < 4; rr++) {
                const int node = n0 + m * 16 + q * 4 + rr;
                const float v = h[(size_t)node * 128 + n] + acc[m][rr] + bb;
                shAgg[(m * 16 + q * 4 + rr) * 136 + n] = f2h(v);
                out[(size_t)node * 128 + n] = v;
            }
    }
    if (tid < 32) {
        const int node = n0 + tid;
        const float ic = 1.0f / fmaxf(cnt[node], 1.0f);
#pragma unroll
        for (int j2 = 0; j2 < 12; j2++)
            out[OUT_X + (size_t)node * 12 + j2] =
                coord[(size_t)node * 12 + j2] + h2f(sAccH[(size_t)node * 12 + j2]) * ic;
    }
    __syncthreads();

    // dual hoisted edge-MLP products: A (h_new tile) loaded once for We1a & We1b
    f32x4 acc1[2], acc2[2];
    acc1[0] = acc1[1] = (f32x4)0.f;
    acc2[0] = acc2[1] = (f32x4)0.f;
#pragma unroll
    for (int c = 0; c < 4; c++) {
        half8 a[2];
#pragma unroll
        for (int m = 0; m < 2; m++)
            a[m] = *(const half8*)(shAgg + (m * 16 + n16) * 136 + c * 32 + ko);
        mfma_c8_dual<2>(We1ap, We1bp, c, wid, q, n16, a, acc1, acc2);
    }
    {
        const int n = wid * 16 + n16;
#pragma unroll
        for (int m = 0; m < 2; m++)
#pragma unroll
            for (int rr = 0; rr < 4; rr++)
                shT[(m * 16 + q * 4 + rr) * 136 + n] = f2h(acc1[m][rr]);
    }
    __syncthreads();
    {
        const int e = tid >> 4, c8 = (tid & 15) * 8;
        *(half8*)(p1h + (size_t)(n0 + e) * 128 + c8) = *(const half8*)(shT + e * 136 + c8);
    }
    __syncthreads();
    {
        const int n = wid * 16 + n16;
#pragma unroll
        for (int m = 0; m < 2; m++)
#pragma unroll
            for (int rr = 0; rr < 4; rr++)
                shT[(m * 16 + q * 4 + rr) * 136 + n] = f2h(acc2[m][rr]);
    }
    __syncthreads();
    {
        const int e = tid >> 4, c8 = (tid & 15) * 8;
        *(half8*)(p2h + (size_t)(n0 + e) * 128 + c8) = *(const half8*)(shT + e * 136 + c8);
    }
}

// ============ edge output m: 4 edges per wave, 16 lanes each, f16 gathers ============
__global__ __launch_bounds__(256) void k_edge(
    const unsigned short* __restrict__ p1h, const unsigned short* __restrict__ p2h,
    const float* __restrict__ eattr, const int* __restrict__ edges,
    const float* __restrict__ We1, const float* __restrict__ be1,
    const float* __restrict__ We2, const float* __restrict__ be2,
    float* __restrict__ mout)
{
    const int tid = threadIdx.x;
    const int lane = tid & 63, wid = tid >> 6;
    const int sub = lane >> 4, l16 = lane & 15;
    const int j = l16 * 8;
    const int g0 = blockIdx.x * 256 + wid * 64;   // wave covers 64 consecutive global edges
    const int r = g0 >> 15;                       // EE = 32768
    const int ebase = g0 & (EE - 1);
    const int* rowsP = edges + r * 2 * EE;
    const int* colsP = rowsP + EE;
    const float* ea = eattr + (size_t)r * EE;

    float w2[8], b1v[8], wm[8];
#pragma unroll
    for (int k = 0; k < 8; k++) {
        w2[k]  = We2[j + k];
        b1v[k] = be1[j + k];
        wm[k]  = We1[128 * 128 + j + k];
    }
    const float b2 = be2[0];

#pragma unroll 4
    for (int it = 0; it < 16; ++it) {
        const int e = ebase + it * 4 + sub;
        const int row = rowsP[e], col = colsP[e];
        const float a = ea[e];
        half8 x1 = *(const half8*)(p1h + (size_t)row * 128 + j);
        half8 x2 = *(const half8*)(p2h + (size_t)col * 128 + j);
        float s = 0.f;
#pragma unroll
        for (int k = 0; k < 8; k++) {
            const float v = (float)x1[k] + (float)x2[k] + a * wm[k] + b1v[k];
            s += silu_f(v) * w2[k];
        }
        s += __shfl_xor(s, 1, 64);
        s += __shfl_xor(s, 2, 64);
        s += __shfl_xor(s, 4, 64);
        s += __shfl_xor(s, 8, 64);
        if (l16 == 0) mout[g0 + it * 4 + sub] = s + b2;
    }
}

extern "C" void kernel_launch(void* const* d_in, const int* in_sizes, int n_in,
                              void* d_out, int out_size, void* d_ws, size_t ws_size,
                              hipStream_t stream)
{
    const float* h     = (const float*)d_in[0];
    const float* coord = (const float*)d_in[1];
    const float* eattr = (const float*)d_in[2];
    const int*   edges = (const int*)d_in[3];
    const float* Wm1 = (const float*)d_in[4];
    const float* bm1 = (const float*)d_in[5];
    const float* Wm2 = (const float*)d_in[6];
    const float* bm2 = (const float*)d_in[7];
    const float* We1 = (const float*)d_in[8];
    const float* be1 = (const float*)d_in[9];
    const float* We2 = (const float*)d_in[10];
    const float* be2 = (const float*)d_in[11];
    const float* Wn1 = (const float*)d_in[12];
    const float* bn1 = (const float*)d_in[13];
    const float* Wn2 = (const float*)d_in[14];
    const float* bn2 = (const float*)d_in[15];
    const float* Wrel = (const float*)d_in[16];
    const float* Wc1 = (const float*)d_in[17];
    const float* bc1 = (const float*)d_in[18];
    const float* Wc2 = (const float*)d_in[19];

    float* out = (float*)d_out;
    float* ws  = (float*)d_ws;

    // f32 zero region: nsq(128) | cnt(20000); f16 zero region: aggh | sAccH
    float* nsq      = ws;             // 128
    float* cnt      = ws + 128;       // 20000 -> f32 region ends at 20128
    unsigned short* U = (unsigned short*)(ws + 20128);
    unsigned short* aggh    = U;                   // 2,560,000 (zeroed, f16 accum)
    unsigned short* sAccH   = U + 2560000;         // 240,000  (zeroed, f16 accum)
    unsigned short* h_bf    = U + 2800000;         // 2,560,000
    unsigned short* H1      = U + 5360000;         // 2,560,000
    unsigned short* H2      = U + 7920000;         // 2,560,000
    unsigned short* p1h     = U + 10480000;        // 2,560,000
    unsigned short* p2h     = U + 13040000;        // 2,560,000
    unsigned short* Wm1ap   = U + 15600000;        // 16,384
    unsigned short* Wm1bp   = U + 15616384;        // 16,384
    unsigned short* Wm1xp   = U + 15632768;        // 4,096
    unsigned short* Wm2p    = U + 15636864;        // 16,384
    unsigned short* Wn1p    = U + 15653248;        // 32,768
    unsigned short* Wn2p    = U + 15686016;        // 16,384
    unsigned short* We1ap   = U + 15702400;        // 16,384
    unsigned short* We1bp   = U + 15718784;        // 16,384
    unsigned short* Wc1p    = U + 15735168;        // 131,072
    unsigned short* Wrelp   = U + 15866240;        // 131,072
    unsigned short* Wc2p    = U + 15997312;        // 16,384 -> ends 16,013,696 shorts

    // cd/radial f16 tables live in DEAD regions (written by k_pre norm path, read by
    // k_msg, overwritten only afterwards by k_node):
    unsigned short* radh = (unsigned short*)out;   // d_out h_new region (8.39 MB)
    unsigned short* cdh  = p1h;                    // p1h/p2h region (8.39 MB)

    // zeroing of [ws, ws + 20128 f32 + 2,800,000 u16) is done inside k_pack_all

    k_pack_all<<<PACK_NB + ZERO_NB, 256, 0, stream>>>(
        Wm1, Wm2, Wn1, Wn2, We1, Wc1, Wrel, Wc2, bm1, ws,
        Wm1ap, Wm1bp, Wm1xp, Wm2p, Wn1p, Wn2p, We1ap, We1bp, Wc1p, Wrelp, Wc2p);
    k_pre<<<PREP_NB + 128, 512, 0, stream>>>(h, coord, edges, Wm1ap, Wm1bp,
        h_bf, H1, H2, nsq, cnt, radh, cdh);
    k_msg<<<dim3(EE / 64, RR), 256, 0, stream>>>(H1, H2, radh, cdh, eattr, edges, nsq,
        Wm1xp, Wm2p, bm2, Wc1p, bc1, Wc2p, Wrelp, sAccH, aggh);
    k_node<<<NN / 32, 512, 0, stream>>>(h, h_bf, coord, aggh, sAccH, cnt,
        Wn1p, bn1, Wn2p, bn2, We1ap, We1bp, out, p1h, p2h);
    k_edge<<<dim3((RR * EE) / 256), 256, 0, stream>>>(p1h, p2h, eattr, edges,
        We1, be1, We2, be2, out + OUT_M);
}